// Round 7
// baseline (246.912 us; speedup 1.0000x reference)
//
#include <hip/hip_runtime.h>
#include <hip/hip_fp16.h>

#define N_NODES 100000
#define N_EDGES 3200000
#define F_IN    128
#define F_HID   32

#define BSHIFT  7
#define BKSZ    128                               // nodes per bucket
#define NBKT    ((N_NODES + BKSZ - 1) / BKSZ)     // 782
#define CAP     5120                              // bucket capacity: mean 4092 + 8 sigma + 4-align pad
#define CHUNK   4096                              // edges per partition block
#define NBLK_E  ((N_EDGES + CHUNK - 1) / CHUNK)   // 782
#define RBITS   17                                // row id bits (100000 < 2^17)
#define RMASK   0x1FFFF
#define NBLK1   ((N_NODES + 63) / 64)             // conv1a/b grid: 64 nodes per block

// fast tanh: 1 - 2/(exp2(x*2/ln2)+1). v_exp_f32 + v_rcp_f32 are ~1ulp approx
// -> abs err ~1e-6, far under the fp16-storage error budget (absmax ~1e-3).
__device__ __forceinline__ float fast_tanh(float x) {
    float t = __builtin_amdgcn_exp2f(x * 2.88539008f);   // e^{2x}
    return 1.0f - 2.0f * __builtin_amdgcn_rcpf(t + 1.0f);
}

// ---------------- coarse partition (fixed-capacity buckets, relative cursors) ----------------
// gcur[] zeroed by hipMemsetAsync; holds per-bucket edge count after k_part.

__global__ __launch_bounds__(512) void k_part(const int* __restrict__ row, const int* __restrict__ col,
                                              int* __restrict__ gcur, unsigned* __restrict__ bkt) {
    __shared__ int hist[NBKT];
    __shared__ int lbase[NBKT];          // local (block) exclusive prefix
    __shared__ int gbase[NBKT];          // global destination base (absolute)
    __shared__ unsigned perm[CHUNK];     // 16 KB: packed words, bucket-major
    __shared__ unsigned short pb[CHUNK]; // 8 KB: bucket id per slot
    __shared__ int wt[8];
    int t = threadIdx.x;
    for (int i = t; i < NBKT; i += 512) hist[i] = 0;
    __syncthreads();

    int e0 = blockIdx.x * CHUNK;
    int n  = min(CHUNK, N_EDGES - e0);
    int r[8], c[8], rk[8];
#pragma unroll
    for (int k = 0; k < 8; k++) {
        int idx = t + k * 512;
        if (idx < n) {
            r[k]  = row[e0 + idx];
            c[k]  = col[e0 + idx];
            rk[k] = atomicAdd(&hist[c[k] >> BSHIFT], 1);   // local rank in bucket
        }
    }
    __syncthreads();

    // block scan: each thread owns 2 consecutive buckets
    {
        int b0 = t * 2;
        int s0 = (b0     < NBKT) ? hist[b0]     : 0;
        int s1 = (b0 + 1 < NBKT) ? hist[b0 + 1] : 0;
        int tsum = s0 + s1;
        int lane = t & 63, wid = t >> 6;
        int incl = tsum;
#pragma unroll
        for (int sh = 1; sh < 64; sh <<= 1) {
            int u = __shfl_up(incl, sh);
            if (lane >= sh) incl += u;
        }
        if (lane == 63) wt[wid] = incl;
        __syncthreads();
        int wpre = 0;
        for (int w = 0; w < wid; w++) wpre += wt[w];
        int excl = wpre + incl - tsum;
        if (b0     < NBKT) lbase[b0]     = excl;
        if (b0 + 1 < NBKT) lbase[b0 + 1] = excl + s0;
    }
    for (int i = t; i < NBKT; i += 512) {
        int h = hist[i];
        gbase[i] = i * CAP + (h ? atomicAdd(&gcur[i], h) : 0);
    }
    __syncthreads();

#pragma unroll
    for (int k = 0; k < 8; k++) {
        int idx = t + k * 512;
        if (idx < n) {
            int b   = c[k] >> BSHIFT;
            int pos = lbase[b] + rk[k];
            perm[pos] = (unsigned)r[k] | ((unsigned)(c[k] & (BKSZ - 1)) << RBITS);
            pb[pos]   = (unsigned short)b;
        }
    }
    __syncthreads();

    for (int i = t; i < n; i += 512) {
        int b = pb[i];
        bkt[gbase[b] + (i - lbase[b])] = perm[i];
    }
}

// ---------------- per-bucket fine sort, IN PLACE (LDS staging), + off/end/dinv ----------------
// Per-node ranges padded to a multiple of 4 (pad entries = N_NODES -> zero-row gathers
// downstream). end[] stores the PADDED end.

__global__ __launch_bounds__(1024) void k_bucket(unsigned* __restrict__ bkt,  // in: bkt, out: srt (aliased)
                                                 const int* __restrict__ gcur,
                                                 int* __restrict__ off, int* __restrict__ end,
                                                 float* __restrict__ dinv) {
    __shared__ unsigned stg[CAP];   // 20 KB staging
    __shared__ int cnt[BKSZ];
    __shared__ int cur[BKSZ];
    __shared__ int wtot[2];
    int t = threadIdx.x, b = blockIdx.x;
    int s = b * CAP, m = gcur[b];   // gcur holds the bucket count
    if (t < BKSZ) cnt[t] = 0;
    __syncthreads();
    for (int i = t; i < m; i += 1024) {
        unsigned x = bkt[s + i];
        stg[i] = x;
        atomicAdd(&cnt[x >> RBITS], 1);
    }
    __syncthreads();

    int lane = t & 63, wid = t >> 6;
    int v = 0, v4 = 0, incl = 0;
    if (t < BKSZ) {
        v  = cnt[t];
        v4 = (v + 3) & ~3;            // padded length
        incl = v4;
        #pragma unroll
        for (int sh = 1; sh < 64; sh <<= 1) {
            int u = __shfl_up(incl, sh);
            if (lane >= sh) incl += u;
        }
        if (lane == 63) wtot[wid] = incl;
    }
    __syncthreads();
    if (t < BKSZ) {
        int wpre = (wid == 1) ? wtot[0] : 0;
        int excl = wpre + incl - v4;
        int base = s + excl;          // 4-aligned
        cur[t] = base;
        int g = b * BKSZ + t;
        if (g < N_NODES) {
            off[g]  = base;
            end[g]  = base + v4;      // PADDED end
            dinv[g] = rsqrtf((float)(v + 1));   // +1 self-loop (real degree)
        }
        for (int j = v; j < v4; j++) bkt[base + j] = N_NODES;   // pad -> zero row id
    }
    __syncthreads();
    for (int i = t; i < m; i += 1024) {
        unsigned x = stg[i];
        int p = atomicAdd(&cur[x >> RBITS], 1);
        bkt[p] = x & RMASK;   // srt: row ids grouped by dest node
    }
}

// ---------------- gemm1: 1 row x 4 feats/thread, DUAL half-tables ----------------
// R18: h1 split feature-wise into two 3.2 MB tables so each conv1 pass gathers from a
// table that fits every XCD's 4 MiB L2 (R17 lesson: 6.4 MB table -> 115 MB L2-miss fill,
// conv1 gather-path-bound at 41 us regardless of VALU work).
// h1a[r*4+f4]   = feats 4f4..4f4+3   (f4 0..3,  feats 0..15)
// h1b[r*4+f4-4] = feats 4f4..4f4+3   (f4 4..7,  feats 16..31)
// Row N_NODES of each = zeros (gather target for pad edges).

__global__ __launch_bounds__(256) void k_gemm1(const float* __restrict__ x, const float* __restrict__ W1,
                                               const float* __restrict__ dinv,
                                               unsigned* __restrict__ h1a, unsigned* __restrict__ h1b) {
    __shared__ float Wlds[F_IN * F_HID];  // 16 KB, [k][f]
    int t = threadIdx.x;
    for (int i = t; i < F_IN * F_HID; i += 256) Wlds[i] = W1[i];
    __syncthreads();

    int gid = blockIdx.x * 256 + t;   // gid = r*8 + f4 ; feats 4f4..4f4+3
    int r = gid >> 3, f4 = gid & 7;
    if (r > N_NODES) return;
    if (r == N_NODES) {               // zero rows for masked gathers
        if (f4 < 4) ((uint2*)h1a)[(size_t)r * 4 + f4]       = make_uint2(0u, 0u);
        else        ((uint2*)h1b)[(size_t)r * 4 + (f4 - 4)] = make_uint2(0u, 0u);
        return;
    }

    const float4* x4  = (const float4*)(x + (size_t)r * F_IN);
    const float4* Wl4 = (const float4*)Wlds;   // [(k)*8 + f4]
    float ax = 0.f, ay = 0.f, az = 0.f, aw = 0.f;
#pragma unroll
    for (int k4 = 0; k4 < F_IN / 4; k4++) {
        float4 xv = x4[k4];
        float4 w0 = Wl4[(4 * k4 + 0) * 8 + f4];
        ax += xv.x * w0.x; ay += xv.x * w0.y; az += xv.x * w0.z; aw += xv.x * w0.w;
        float4 w1 = Wl4[(4 * k4 + 1) * 8 + f4];
        ax += xv.y * w1.x; ay += xv.y * w1.y; az += xv.y * w1.z; aw += xv.y * w1.w;
        float4 w2 = Wl4[(4 * k4 + 2) * 8 + f4];
        ax += xv.z * w2.x; ay += xv.z * w2.y; az += xv.z * w2.z; aw += xv.z * w2.w;
        float4 w3 = Wl4[(4 * k4 + 3) * 8 + f4];
        ax += xv.w * w3.x; ay += xv.w * w3.y; az += xv.w * w3.z; aw += xv.w * w3.w;
    }
    float di = dinv[r];
    unsigned p01 = (unsigned)__half_as_ushort(__float2half(di * ax))
                 | ((unsigned)__half_as_ushort(__float2half(di * ay)) << 16);
    unsigned p23 = (unsigned)__half_as_ushort(__float2half(di * az))
                 | ((unsigned)__half_as_ushort(__float2half(di * aw)) << 16);
    if (f4 < 4) ((uint2*)h1a)[(size_t)r * 4 + f4]       = make_uint2(p01, p23);
    else        ((uint2*)h1b)[(size_t)r * 4 + (f4 - 4)] = make_uint2(p01, p23);
}

// ---------------- conv1a R18: 16 nodes/wave, gathers ONLY h1a (3.2 MB, L2-resident) ------
// lane = q*4 + o... actually q = lane>>2 (node slot 0..15), o = lane&3 (feat quad of A-half:
// feats 4o..4o+3). Inner loop identical shape to R17 (uniform int4 srt broadcast per quad,
// uint2 gathers, 16 cvt-adds/lane/iter). Epilogue: store raw f32 partial sums (no tanh).

__global__ __launch_bounds__(256) void k_conv1a(const int* __restrict__ off, const int* __restrict__ end,
                                                const int* __restrict__ srt,
                                                const unsigned* __restrict__ h1a,
                                                float* __restrict__ part) {
    int t = threadIdx.x;
    int lane = t & 63, wid = t >> 6;
    int q = lane >> 2, o = lane & 3;
    int c = (blockIdx.x * 4 + wid) * 16 + q;
    int cs = (c < N_NODES) ? c : N_NODES;
    int b = 0, ep = 0;
    if (c < N_NODES) { b = off[c]; ep = end[c]; }

    const char* hb = (const char*)h1a;
    unsigned oo = (unsigned)(o << 3);
    uint2 sv = *(const uint2*)(hb + (((unsigned)cs << 5) + oo));   // self row (32 B rows)

    float a0a = 0.f, a1a = 0.f, a2a = 0.f, a3a = 0.f;
    float a0b = 0.f, a1b = 0.f, a2b = 0.f, a3b = 0.f;
    float a0c = 0.f, a1c = 0.f, a2c = 0.f, a3c = 0.f;
    float a0d = 0.f, a1d = 0.f, a2d = 0.f, a3d = 0.f;

    int p = b;
    while (__any(p < ep)) {
        int r0 = N_NODES, r1 = N_NODES, r2 = N_NODES, r3 = N_NODES;
        if (p < ep) {
            int4 rs = *(const int4*)(srt + p);
            r0 = rs.x; r1 = rs.y; r2 = rs.z; r3 = rs.w;
        }
        uint2 v0 = *(const uint2*)(hb + (((unsigned)r0 << 5) + oo));
        uint2 v1 = *(const uint2*)(hb + (((unsigned)r1 << 5) + oo));
        uint2 v2 = *(const uint2*)(hb + (((unsigned)r2 << 5) + oo));
        uint2 v3 = *(const uint2*)(hb + (((unsigned)r3 << 5) + oo));
        a0a += __low2float(*(const __half2*)&v0.x);  a1a += __high2float(*(const __half2*)&v0.x);
        a2a += __low2float(*(const __half2*)&v0.y);  a3a += __high2float(*(const __half2*)&v0.y);
        a0b += __low2float(*(const __half2*)&v1.x);  a1b += __high2float(*(const __half2*)&v1.x);
        a2b += __low2float(*(const __half2*)&v1.y);  a3b += __high2float(*(const __half2*)&v1.y);
        a0c += __low2float(*(const __half2*)&v2.x);  a1c += __high2float(*(const __half2*)&v2.x);
        a2c += __low2float(*(const __half2*)&v2.y);  a3c += __high2float(*(const __half2*)&v2.y);
        a0d += __low2float(*(const __half2*)&v3.x);  a1d += __high2float(*(const __half2*)&v3.x);
        a2d += __low2float(*(const __half2*)&v3.y);  a3d += __high2float(*(const __half2*)&v3.y);
        p += 4;
    }

    float f0 = (a0a + a0b) + (a0c + a0d) + __low2float(*(const __half2*)&sv.x);
    float f1 = (a1a + a1b) + (a1c + a1d) + __high2float(*(const __half2*)&sv.x);
    float f2 = (a2a + a2b) + (a2c + a2d) + __low2float(*(const __half2*)&sv.y);
    float f3 = (a3a + a3b) + (a3c + a3d) + __high2float(*(const __half2*)&sv.y);

    if (c < N_NODES)
        *(float4*)(part + ((size_t)c << 4) + (o << 2)) = make_float4(f0, f1, f2, f3);
}

// ---------------- conv1b R18: gathers ONLY h1b, + epilogue (tanh, @W2, store) ----------
// Lane o holds B-half feats 16+4o..16+4o+3 (own sums) and A-half feats 4o..4o+3 (loaded
// from part). 8 tanh + 24 fma + 2-level butterfly over the quad -> h2s4.

__global__ __launch_bounds__(256) void k_conv1b(const int* __restrict__ off, const int* __restrict__ end,
                                                const int* __restrict__ srt, const float* __restrict__ dinv,
                                                const unsigned* __restrict__ h1b,
                                                const float* __restrict__ part,
                                                const float* __restrict__ W2, float* __restrict__ h2s4) {
    int t = threadIdx.x;
    if (blockIdx.x == 0 && t < 4) h2s4[(size_t)N_NODES * 4 + t] = 0.0f;  // zero row for k_conv2
    int lane = t & 63, wid = t >> 6;
    int q = lane >> 2, o = lane & 3;
    int c = (blockIdx.x * 4 + wid) * 16 + q;
    int cs = (c < N_NODES) ? c : N_NODES;
    int b = 0, ep = 0;
    if (c < N_NODES) { b = off[c]; ep = end[c]; }

    const char* hb = (const char*)h1b;
    unsigned oo = (unsigned)(o << 3);
    uint2 sv = *(const uint2*)(hb + (((unsigned)cs << 5) + oo));

    float a0a = 0.f, a1a = 0.f, a2a = 0.f, a3a = 0.f;
    float a0b = 0.f, a1b = 0.f, a2b = 0.f, a3b = 0.f;
    float a0c = 0.f, a1c = 0.f, a2c = 0.f, a3c = 0.f;
    float a0d = 0.f, a1d = 0.f, a2d = 0.f, a3d = 0.f;

    int p = b;
    while (__any(p < ep)) {
        int r0 = N_NODES, r1 = N_NODES, r2 = N_NODES, r3 = N_NODES;
        if (p < ep) {
            int4 rs = *(const int4*)(srt + p);
            r0 = rs.x; r1 = rs.y; r2 = rs.z; r3 = rs.w;
        }
        uint2 v0 = *(const uint2*)(hb + (((unsigned)r0 << 5) + oo));
        uint2 v1 = *(const uint2*)(hb + (((unsigned)r1 << 5) + oo));
        uint2 v2 = *(const uint2*)(hb + (((unsigned)r2 << 5) + oo));
        uint2 v3 = *(const uint2*)(hb + (((unsigned)r3 << 5) + oo));
        a0a += __low2float(*(const __half2*)&v0.x);  a1a += __high2float(*(const __half2*)&v0.x);
        a2a += __low2float(*(const __half2*)&v0.y);  a3a += __high2float(*(const __half2*)&v0.y);
        a0b += __low2float(*(const __half2*)&v1.x);  a1b += __high2float(*(const __half2*)&v1.x);
        a2b += __low2float(*(const __half2*)&v1.y);  a3b += __high2float(*(const __half2*)&v1.y);
        a0c += __low2float(*(const __half2*)&v2.x);  a1c += __high2float(*(const __half2*)&v2.x);
        a2c += __low2float(*(const __half2*)&v2.y);  a3c += __high2float(*(const __half2*)&v2.y);
        a0d += __low2float(*(const __half2*)&v3.x);  a1d += __high2float(*(const __half2*)&v3.x);
        a2d += __low2float(*(const __half2*)&v3.y);  a3d += __high2float(*(const __half2*)&v3.y);
        p += 4;
    }
    if (c >= N_NODES) return;   // whole quad exits together; butterflies stay quad-local

    float f0 = (a0a + a0b) + (a0c + a0d) + __low2float(*(const __half2*)&sv.x);
    float f1 = (a1a + a1b) + (a1c + a1d) + __high2float(*(const __half2*)&sv.x);
    float f2 = (a2a + a2b) + (a2c + a2d) + __low2float(*(const __half2*)&sv.y);
    float f3 = (a3a + a3b) + (a3c + a3d) + __high2float(*(const __half2*)&sv.y);

    float4 pa = *(const float4*)(part + ((size_t)c << 4) + (o << 2));
    float di = dinv[c];
    float hA0 = fast_tanh(di * pa.x), hA1 = fast_tanh(di * pa.y);
    float hA2 = fast_tanh(di * pa.z), hA3 = fast_tanh(di * pa.w);
    float hB0 = fast_tanh(di * f0),   hB1 = fast_tanh(di * f1);
    float hB2 = fast_tanh(di * f2),   hB3 = fast_tanh(di * f3);

    const float* WA = W2 + (o << 2) * 3;          // A feats 4o..4o+3
    const float* WB = W2 + (16 + (o << 2)) * 3;   // B feats 16+4o..16+4o+3
    float p0 = hA0 * WA[0] + hA1 * WA[3] + hA2 * WA[6] + hA3 * WA[9]
             + hB0 * WB[0] + hB1 * WB[3] + hB2 * WB[6] + hB3 * WB[9];
    float p1 = hA0 * WA[1] + hA1 * WA[4] + hA2 * WA[7] + hA3 * WA[10]
             + hB0 * WB[1] + hB1 * WB[4] + hB2 * WB[7] + hB3 * WB[10];
    float p2 = hA0 * WA[2] + hA1 * WA[5] + hA2 * WA[8] + hA3 * WA[11]
             + hB0 * WB[2] + hB1 * WB[5] + hB2 * WB[8] + hB3 * WB[11];
#pragma unroll
    for (int m = 1; m <= 2; m <<= 1) {            // reduce over the 4 quad lanes
        p0 += __shfl_xor(p0, m);
        p1 += __shfl_xor(p1, m);
        p2 += __shfl_xor(p2, m);
    }
    float vv = (o == 0) ? p0 : (o == 1) ? p1 : (o == 2) ? p2 : 0.0f;
    h2s4[(size_t)c * 4 + o] = (o < 3) ? di * vv : 0.0f;   // slot 3 = real 0
}

// ---------------- conv2: 4 lanes/node, maskless padded ranges (R17, unchanged) ----------

__global__ __launch_bounds__(256) void k_conv2(const int* __restrict__ off, const int* __restrict__ end,
                                               const int* __restrict__ srt, const float* __restrict__ dinv,
                                               const float* __restrict__ h2s4, float* __restrict__ out) {
    int gt = blockIdx.x * 256 + threadIdx.x;
    int c = gt >> 2, j = gt & 3;
    if (c >= N_NODES) return;

    const float4* h2v = (const float4*)h2s4;
    int b = off[c], ep = end[c];             // padded, b % 4 == 0
    float4 sv = h2v[c];                      // self-loop term (w component = 0)
    float ax = (j == 0) ? sv.x : 0.0f;
    float ay = (j == 0) ? sv.y : 0.0f;
    float az = (j == 0) ? sv.z : 0.0f;

    for (int p = b + 4 * j; p < ep; p += 16) {
        int4 rs = *(const int4*)(srt + p);
        float4 v0 = h2v[rs.x];
        float4 v1 = h2v[rs.y];
        float4 v2 = h2v[rs.z];
        float4 v3 = h2v[rs.w];
        ax += (v0.x + v1.x) + (v2.x + v3.x);
        ay += (v0.y + v1.y) + (v2.y + v3.y);
        az += (v0.z + v1.z) + (v2.z + v3.z);
    }
#pragma unroll
    for (int m = 1; m <= 2; m <<= 1) {       // reduce over the 4 quad lanes
        ax += __shfl_xor(ax, m);
        ay += __shfl_xor(ay, m);
        az += __shfl_xor(az, m);
    }

    float di = dinv[c];
    if (j < 3) {
        float a = (j == 0) ? ax : (j == 1) ? ay : az;
        out[(size_t)c * 3 + j] = di * a;     // 3 consecutive lanes -> coalesced
    }
}

// ---------------- launch ----------------

extern "C" void kernel_launch(void* const* d_in, const int* in_sizes, int n_in,
                              void* d_out, int out_size, void* d_ws, size_t ws_size,
                              hipStream_t stream) {
    const float* x   = (const float*)d_in[0];
    const int*   ei  = (const int*)d_in[1];  // [2, E] int32
    const float* W1  = (const float*)d_in[2];
    const float* W2  = (const float*)d_in[3];
    float*       out = (float*)d_out;

    const int* row = ei;
    const int* col = ei + N_EDGES;

    char* ws = (char*)d_ws;
    unsigned* bkt = (unsigned*)ws;
    int*      srt = (int*)ws;                 // alias (in-place after k_bucket)
    char*     p   = ws + 4ull * NBKT * CAP;
    int*      gcur = (int*)p;                 p += 4ull * ((NBKT + 63) & ~63);
    int*      off  = (int*)p;                 p += 4ull * N_NODES;
    int*      end  = (int*)p;                 p += 4ull * N_NODES;
    float*    dinv = (float*)p;               p += 4ull * N_NODES;
    unsigned* h1a  = (unsigned*)p;            p += 32ull * (N_NODES + 2);  // 3.2 MB + zero row
    unsigned* h1b  = (unsigned*)p;            p += 32ull * (N_NODES + 2);  // 3.2 MB + zero row
    float*    part = (float*)p;               p += 64ull * N_NODES;        // f32 partials (A half)
    float*    h2s4 = (float*)p;               // N_NODES+1 rows (zero row for conv2 masks)

    const int B = 256;
    hipMemsetAsync(gcur, 0, 4ull * NBKT, stream);
    hipLaunchKernelGGL(k_part,   dim3(NBLK_E), dim3(512),  0, stream, row, col, gcur, bkt);
    hipLaunchKernelGGL(k_bucket, dim3(NBKT),   dim3(1024), 0, stream, bkt, gcur, off, end, dinv);
    hipLaunchKernelGGL(k_gemm1,  dim3(((N_NODES + 1) * 8 + B - 1) / B), dim3(B), 0, stream,
                       x, W1, dinv, h1a, h1b);
    hipLaunchKernelGGL(k_conv1a, dim3(NBLK1), dim3(B), 0, stream, off, end, srt, h1a, part);
    hipLaunchKernelGGL(k_conv1b, dim3(NBLK1), dim3(B), 0, stream,
                       off, end, srt, dinv, h1b, part, W2, h2s4);
    hipLaunchKernelGGL(k_conv2,  dim3((4 * N_NODES + B - 1) / B), dim3(B), 0, stream,
                       off, end, srt, dinv, h2s4, out);
}